// Round 5
// baseline (65.455 us; speedup 1.0000x reference)
//
#include <hip/hip_runtime.h>
#include <hip/hip_fp16.h>

#define NN   2048
#define FIN  128
#define FOUT 64
#define LOG2E 1.44269504088896f

using f16x8 = __attribute__((ext_vector_type(8))) _Float16;
using f16x4 = __attribute__((ext_vector_type(4))) _Float16;
using f16x2 = __attribute__((ext_vector_type(2))) _Float16;
using f32x4 = __attribute__((ext_vector_type(4))) float;
using i32x4 = __attribute__((ext_vector_type(4))) int;

__device__ inline float fast_exp2(float x) {
#if __has_builtin(__builtin_amdgcn_exp2f)
    return __builtin_amdgcn_exp2f(x);
#else
    return exp2f(x);
#endif
}

// h16B frag-ordered layout, per (bh): halves offset =
//   bh*131072 + (j>>5)*2048 + (o>>4)*512 + (((j>>3)&3)*16 + (o&15))*8 + (j&7)
// = 16x16x32 MFMA B-fragment order (n = lane&15, k = 8*(lane>>4)+i).

// ---------------------------------------------------------------------------
// Kernel 1: h = x @ w[h] (fp32), fused tanh -> s_src/s_dst (pre-scaled by
// log2e), h -> fp16 frag order.  512 blocks x 256 threads.
// ---------------------------------------------------------------------------
__global__ __launch_bounds__(256) void k1_proj(
    const float* __restrict__ x, const float* __restrict__ w,
    const float* __restrict__ a_src, const float* __restrict__ a_dst,
    _Float16* __restrict__ h16B, float* __restrict__ ssrc, float* __restrict__ sdst)
{
    __shared__ __align__(16) float w_s[FIN * FOUT];
    __shared__ __align__(16) float xs[64 * 132];

    const int t    = threadIdx.x;
    const int bx   = blockIdx.x;
    const int bh   = bx >> 5;
    const int tile = bx & 31;
    const int b    = bh >> 2;
    const int h    = bh & 3;
    const int n0   = tile * 64;

    {
        const f32x4* wg = (const f32x4*)(w + h * FIN * FOUT);
        f32x4* wl = (f32x4*)w_s;
#pragma unroll
        for (int k = 0; k < 8; ++k) wl[t + 256 * k] = wg[t + 256 * k];
    }
    {
#pragma unroll
        for (int k = 0; k < 8; ++k) {
            int q  = t + 256 * k;
            int r  = q >> 5;
            int c4 = q & 31;
            f32x4 v = *(const f32x4*)(x + (size_t)(b * NN + n0 + r) * FIN + c4 * 4);
            *(f32x4*)(xs + r * 132 + c4 * 4) = v;
        }
    }
    __syncthreads();

    const int ty = t >> 4, tx = t & 15;
    float acc[4][4] = {};

#pragma unroll 4
    for (int f4 = 0; f4 < 32; ++f4) {
        f32x4 xv[4], wv[4];
#pragma unroll
        for (int q = 0; q < 4; ++q)
            xv[q] = *(const f32x4*)(xs + (ty * 4 + q) * 132 + f4 * 4);
#pragma unroll
        for (int k = 0; k < 4; ++k)
            wv[k] = *(const f32x4*)(w_s + (f4 * 4 + k) * 64 + tx * 4);
#pragma unroll
        for (int q = 0; q < 4; ++q)
#pragma unroll
            for (int k = 0; k < 4; ++k)
#pragma unroll
                for (int c = 0; c < 4; ++c)
                    acc[q][c] += xv[q][k] * wv[k][c];
    }

    const int j0 = n0 + ty * 4;
#pragma unroll
    for (int cc = 0; cc < 4; ++cc) {
        int o = tx * 4 + cc;
        f16x4 hv;
#pragma unroll
        for (int q = 0; q < 4; ++q) hv[q] = (_Float16)acc[q][cc];
        int off = bh * 131072 + (j0 >> 5) * 2048 + (o >> 4) * 512
                + (((j0 >> 3) & 3) * 16 + (o & 15)) * 8 + (j0 & 7);
        *(f16x4*)(h16B + off) = hv;
    }

    f32x4 a_s = *(const f32x4*)(a_src + h * FOUT + tx * 4);
    f32x4 a_d = *(const f32x4*)(a_dst + h * FOUT + tx * 4);
    float ss[4], sd[4];
#pragma unroll
    for (int q = 0; q < 4; ++q) {
        float s1 = 0.f, s2 = 0.f;
#pragma unroll
        for (int cc = 0; cc < 4; ++cc) {
            float th = tanhf(acc[q][cc]);
            s1 += th * a_s[cc];
            s2 += th * a_d[cc];
        }
        ss[q] = s1; sd[q] = s2;
    }
#pragma unroll
    for (int m = 1; m <= 8; m <<= 1) {
#pragma unroll
        for (int q = 0; q < 4; ++q) {
            ss[q] += __shfl_xor(ss[q], m);
            sd[q] += __shfl_xor(sd[q], m);
        }
    }
    if (tx == 0) {
#pragma unroll
        for (int q = 0; q < 4; ++q) {
            ssrc[bh * NN + j0 + q] = ss[q] * LOG2E;   // pre-scale: exp -> exp2
            sdst[bh * NN + j0 + q] = sd[q] * LOG2E;
        }
    }
}

// ---------------------------------------------------------------------------
// Kernel 2: barrier-FREE masked-softmax attention + PV (fp16 MFMA).
// 1024 blocks (16 bh x 64 row-tiles of 32), 256 threads = 4 waves.
// wave wv: rg=wv>>1 -> rows i0+rg*16+(lane&15); par=wv&1 -> chunk parity.
// All operands (adj, B-fragments) register-double-buffered via direct global
// loads; NO LDS staging, NO barriers in main loop -> waves free-run.
// ---------------------------------------------------------------------------
__global__ __launch_bounds__(256, 4) void k2_attn(
    const int* __restrict__ adj,
    const _Float16* __restrict__ h16B,
    const float* __restrict__ ssrc, const float* __restrict__ sdst,
    const float* __restrict__ bias, float* __restrict__ out)
{
    __shared__ __align__(16) float sd_lds[NN];          // 8KB
    __shared__ __align__(16) float comb[2][64][21];     // parity-combine, 10.5KB
    __shared__ float redmax[4];

    const int t    = threadIdx.x;
    const int wv   = t >> 6;
    const int lane = t & 63;
    const int bh   = blockIdx.x >> 6;
    const int i0   = (blockIdx.x & 63) << 5;
    const int b    = bh >> 2;
    const int rg   = wv >> 1;
    const int par  = wv & 1;
    const int m    = lane & 15;
    const int g    = lane >> 4;

    // ---- stage sdst (scaled) into LDS + block max D ----
    {
        const float* sdp = sdst + bh * NN;
        float dm = -1e30f;
#pragma unroll
        for (int k = 0; k < 8; ++k) {
            float v = sdp[t + 256 * k];
            sd_lds[t + 256 * k] = v;
            dm = fmaxf(dm, v);
        }
#pragma unroll
        for (int msk = 1; msk <= 32; msk <<= 1) dm = fmaxf(dm, __shfl_xor(dm, msk));
        if (lane == 0) redmax[wv] = dm;
    }
    __syncthreads();
    const float D = fmaxf(fmaxf(redmax[0], redmax[1]), fmaxf(redmax[2], redmax[3]));

    const int row = i0 + rg * 16 + m;
    const float sA = ssrc[bh * NN + row];
    float c = sA + D; c = fmaxf(c, 0.2f * c);          // leaky(sA+D) >= row max logit
    const float sAc  = sA - c;
    const float sAc2 = fmaf(0.2f, sA, -c);

    const int* adjrow = adj + ((size_t)b * NN + row) * NN + 8 * g;
    const _Float16* Bsrc = h16B + bh * 131072 + lane * 8;

    f32x4 acc0 = {0,0,0,0}, acc1 = {0,0,0,0}, acc2 = {0,0,0,0}, acc3 = {0,0,0,0};
    f32x4 accz = {0,0,0,0};
    f16x8 ones;
#pragma unroll
    for (int i = 0; i < 8; ++i) ones[i] = (_Float16)1.0f;

    // register double buffers (statically named -> no scratch)
    i32x4 avA0, avA1, avB0, avB1;
    f16x8 bA0, bA1, bA2, bA3, bB0, bB1, bB2, bB3;

#define LOADP(av0_, av1_, b0_, b1_, b2_, b3_, it_) do {                       \
        const int jb_ = ((it_) * 2 + par) * 32;                               \
        av0_ = *(const i32x4*)(adjrow + jb_);                                 \
        av1_ = *(const i32x4*)(adjrow + jb_ + 4);                             \
        const _Float16* bb_ = Bsrc + ((it_) * 2 + par) * 2048;                \
        b0_ = *(const f16x8*)(bb_);                                           \
        b1_ = *(const f16x8*)(bb_ + 512);                                     \
        b2_ = *(const f16x8*)(bb_ + 1024);                                    \
        b3_ = *(const f16x8*)(bb_ + 1536);                                    \
    } while (0)

#define COMPUTE(av0_, av1_, b0_, b1_, b2_, b3_, it_) do {                     \
        const int jb_ = ((it_) * 2 + par) * 32;                               \
        const float* djp_ = sd_lds + jb_ + 8 * g;                             \
        f32x4 dj0_ = *(const f32x4*)(djp_);                                   \
        f32x4 dj1_ = *(const f32x4*)(djp_ + 4);                               \
        float ev_[8];                                                         \
        _Pragma("unroll")                                                     \
        for (int i = 0; i < 8; ++i) {                                         \
            float dj = (i < 4) ? dj0_[i] : dj1_[i - 4];                       \
            int   av = (i < 4) ? av0_[i] : av1_[i - 4];                       \
            float a1 = sAc + dj;                                              \
            float a2 = fmaf(0.2f, dj, sAc2);                                  \
            float ee = fast_exp2(fmaxf(a1, a2));                              \
            ev_[i] = av ? ee : 0.0f;                                          \
        }                                                                     \
        union { f16x8 v; f16x2 p[4]; } af_;                                   \
        _Pragma("unroll")                                                     \
        for (int i = 0; i < 4; ++i)                                           \
            af_.p[i] = __builtin_bit_cast(f16x2,                              \
                __builtin_amdgcn_cvt_pkrtz(ev_[2 * i], ev_[2 * i + 1]));      \
        acc0 = __builtin_amdgcn_mfma_f32_16x16x32_f16(af_.v, b0_, acc0, 0, 0, 0); \
        acc1 = __builtin_amdgcn_mfma_f32_16x16x32_f16(af_.v, b1_, acc1, 0, 0, 0); \
        acc2 = __builtin_amdgcn_mfma_f32_16x16x32_f16(af_.v, b2_, acc2, 0, 0, 0); \
        acc3 = __builtin_amdgcn_mfma_f32_16x16x32_f16(af_.v, b3_, acc3, 0, 0, 0); \
        accz = __builtin_amdgcn_mfma_f32_16x16x32_f16(af_.v, ones, accz, 0, 0, 0); \
    } while (0)

    LOADP(avA0, avA1, bA0, bA1, bA2, bA3, 0);
    LOADP(avB0, avB1, bB0, bB1, bB2, bB3, 1);

    for (int ii = 0; ii < 15; ++ii) {
        const int it0 = 2 * ii;
        COMPUTE(avA0, avA1, bA0, bA1, bA2, bA3, it0);
        LOADP(avA0, avA1, bA0, bA1, bA2, bA3, it0 + 2);
        COMPUTE(avB0, avB1, bB0, bB1, bB2, bB3, it0 + 1);
        LOADP(avB0, avB1, bB0, bB1, bB2, bB3, it0 + 3);
    }
    COMPUTE(avA0, avA1, bA0, bA1, bA2, bA3, 30);
    COMPUTE(avB0, avB1, bB0, bB1, bB2, bB3, 31);

#undef LOADP
#undef COMPUTE

    // ---- combine parity partials ----
    __syncthreads();
    if (par == 1) {
        float* cp = &comb[rg][lane][0];
#pragma unroll
        for (int r = 0; r < 4; ++r) {
            cp[0 + r]  = acc0[r];
            cp[4 + r]  = acc1[r];
            cp[8 + r]  = acc2[r];
            cp[12 + r] = acc3[r];
            cp[16 + r] = accz[r];
        }
    }
    __syncthreads();
    if (par == 0) {
        const float* cp = &comb[rg][lane][0];
        float zs[4];
#pragma unroll
        for (int r = 0; r < 4; ++r) zs[r] = accz[r] + cp[16 + r];
        size_t obase = ((size_t)bh * NN + i0 + rg * 16) * FOUT;
#pragma unroll
        for (int ot = 0; ot < 4; ++ot) {
            float bv = bias[ot * 16 + m];
            f32x4 a = (ot == 0) ? acc0 : (ot == 1) ? acc1 : (ot == 2) ? acc2 : acc3;
#pragma unroll
            for (int r = 0; r < 4; ++r) {
                float v = (a[r] + cp[ot * 4 + r]) / zs[r] + bv;
                out[obase + (size_t)(g * 4 + r) * FOUT + ot * 16 + m] = v;
            }
        }
    }
}

// ---------------------------------------------------------------------------
extern "C" void kernel_launch(void* const* d_in, const int* in_sizes, int n_in,
                              void* d_out, int out_size, void* d_ws, size_t ws_size,
                              hipStream_t stream) {
    (void)in_sizes; (void)n_in; (void)out_size; (void)ws_size;
    const float* x     = (const float*)d_in[0];
    const int*   adj   = (const int*)d_in[1];     // bool -> int32
    const float* w     = (const float*)d_in[2];
    const float* a_src = (const float*)d_in[3];
    const float* a_dst = (const float*)d_in[4];
    const float* bias  = (const float*)d_in[5];
    float*       out   = (float*)d_out;

    _Float16* h16B = (_Float16*)d_ws;                              // 4 MB
    float*    ssrc = (float*)((char*)d_ws + 4194304);              // 128 KB
    float*    sdst = (float*)((char*)d_ws + 4194304 + 131072);     // 128 KB

    k1_proj<<<512, 256, 0, stream>>>(x, w, a_src, a_dst, h16B, ssrc, sdst);
    k2_attn<<<1024, 256, 0, stream>>>(adj, h16B, ssrc, sdst, bias, out);
}